// Round 5
// baseline (272.690 us; speedup 1.0000x reference)
//
#include <hip/hip_runtime.h>

#define NOUT 7
#define NROI 512
#define NCH 256
#define BINS (NOUT * NOUT)        // 49
#define ROI_ELEMS (NCH * BINS)    // 12544
#define G 4                       // channels per block
#define NGROUP (NCH / G)          // 64 channel groups
#define WINCAP 1248               // floats per channel window (worst case ~1080)

__global__ __launch_bounds__(256) void roi_pool_kernel(
    const float* __restrict__ x2,
    const float* __restrict__ x3,
    const float* __restrict__ x4,
    const float* __restrict__ x5,
    const float* __restrict__ boxes,
    float* __restrict__ out)
{
    const int r  = blockIdx.x;   // roi 0..511
    const int cg = blockIdx.y;   // channel group 0..63
    const int t  = threadIdx.x;  // 0..255

    // 4 * 1248 * 4 = 19968 B + descriptors: total 20456 <= 20480 -> 8 blocks/CU
    __shared__ float win[G * WINCAP];
    __shared__ float4 sdy[14];       // { asfloat(rowrel*ldsw), fy, 0.25*vy, 0 }
    __shared__ float4 sdx[14];       // { asfloat(colrel),      fx, vx,      0 }
    __shared__ int sgeo[7];          // nrows, ldsw, span2, lpr2-1, shift2, W, HW
    __shared__ const float* sbase;   // feat + b*C*H*W + y0min*W + x0min

    if (t < 32) {
        const float bx1 = boxes[4 * r + 0];
        const float by1 = boxes[4 * r + 1];
        const float bx2 = boxes[4 * r + 2];
        const float by2 = boxes[4 * r + 3];
        const float sz  = sqrtf((bx2 - bx1) * (by2 - by1));
        float lvlf = floorf(4.0f + log2f(sz / 224.0f + 1e-8f));
        lvlf = fminf(fmaxf(lvlf, 2.0f), 5.0f);
        const int level = (int)lvlf - 2;

        int H, W; float scale; const float* feat;
        if (level == 0)      { H = 200; W = 304; scale = 0.25f;    feat = x2; }
        else if (level == 1) { H = 100; W = 152; scale = 0.125f;   feat = x3; }
        else if (level == 2) { H = 50;  W = 76;  scale = 0.0625f;  feat = x4; }
        else                 { H = 25;  W = 38;  scale = 0.03125f; feat = x5; }

        const float X1 = bx1 * scale - 0.5f;
        const float Y1 = by1 * scale - 0.5f;
        const float X2 = bx2 * scale - 0.5f;
        const float Y2 = by2 * scale - 0.5f;
        const float bw = (X2 - X1) * (1.0f / NOUT);
        const float bh = (Y2 - Y1) * (1.0f / NOUT);

        // i0 of a sample coord (normalized so i1 = i0+1 always; same math as R3)
        auto i0_of = [](float c, int size) -> int {
            c = fminf(fmaxf(c, 0.0f), (float)(size - 1));
            return min((int)floorf(c), size - 2);
        };
        // sample grid is monotonic -> extremes are samples 0 and 13
        const int y0min = i0_of(Y1 + 0.25f * bh, H);
        const int y0max = i0_of(Y1 + 6.75f * bh, H);
        const int x0max = i0_of(X1 + 6.75f * bw, W);
        int x0min = i0_of(X1 + 0.25f * bw, W) & ~1;        // even (float2 align)
        int span  = x0max - x0min + 2;
        span = (span + 1) & ~1;                            // even; stays <= W-x0min
        const int ldsw  = span + 1;                        // odd -> bank destagger
        const int nrows = y0max - y0min + 2;
        const int span2 = span >> 1;                       // float2 per row
        int lpr2 = 4;                                      // pow2 lanes per row
        while (lpr2 < span2) lpr2 <<= 1;
        const int shift2 = 31 - __clz(lpr2);

        if (t < 14) {
            const float g = 0.25f + 0.5f * (float)t;
            float c = Y1 + g * bh;
            const bool valid = (c >= -1.0f) && (c <= (float)H);
            c = fminf(fmaxf(c, 0.0f), (float)(H - 1));
            int i0 = min((int)floorf(c), H - 2);
            sdy[t] = make_float4(__int_as_float((i0 - y0min) * ldsw),
                                 c - (float)i0,
                                 valid ? 0.25f : 0.0f, 0.0f);
        } else if (t >= 16 && t < 30) {
            const int k = t - 16;
            const float g = 0.25f + 0.5f * (float)k;
            float c = X1 + g * bw;
            const bool valid = (c >= -1.0f) && (c <= (float)W);
            c = fminf(fmaxf(c, 0.0f), (float)(W - 1));
            int i0 = min((int)floorf(c), W - 2);
            sdx[k] = make_float4(__int_as_float(i0 - x0min),
                                 c - (float)i0,
                                 valid ? 1.0f : 0.0f, 0.0f);
        } else if (t == 31) {
            sgeo[0] = nrows;
            sgeo[1] = ldsw;
            sgeo[2] = span2;
            sgeo[3] = lpr2 - 1;
            sgeo[4] = shift2;
            sgeo[5] = W;
            sgeo[6] = H * W;
            const int b = r >> 8;
            sbase = feat + (size_t)b * NCH * H * W + (size_t)(y0min * W + x0min);
        }
    }
    __syncthreads();

    const int nrows  = sgeo[0];
    const int ldsw   = sgeo[1];
    const int span2  = sgeo[2];
    const int lprm1  = sgeo[3];
    const int shift2 = sgeo[4];
    const int W      = sgeo[5];
    const int HW     = sgeo[6];
    const float* const base = sbase;
    const int c0 = cg * G;

    // ---- stage G channel windows: float2 per lane, coalesced rows ----
    const int slots = nrows << shift2;    // nrows * lpr2
    #pragma unroll
    for (int c = 0; c < G; ++c) {
        const float* src = base + (size_t)(c0 + c) * HW;
        float* dst = win + c * WINCAP;
        for (int id = t; id < slots; id += 256) {
            const int row = id >> shift2;
            const int c2  = id & lprm1;
            if (c2 < span2) {
                const float2 v = *(const float2*)(src + row * W + 2 * c2);
                const int a = row * ldsw + 2 * c2;
                dst[a]     = v.x;        // adjacent pair -> ds_write2_b32
                dst[a + 1] = v.y;
            }
        }
    }
    __syncthreads();

    // ---- compute: 4 channels x 49 bins from LDS ----
    if (t < G * BINS) {
        const int cl  = t / BINS;
        const int bin = t - cl * BINS;
        const int ph  = bin / NOUT;
        const int pw  = bin - ph * NOUT;

        const float4 dy0 = sdy[ph * 2 + 0];
        const float4 dy1 = sdy[ph * 2 + 1];
        const float4 dx0 = sdx[pw * 2 + 0];
        const float4 dx1 = sdx[pw * 2 + 1];
        const float* const w0 = win + cl * WINCAP;

        float acc = 0.0f;
        #pragma unroll
        for (int sy = 0; sy < 2; ++sy) {
            const float4 dy = sy ? dy1 : dy0;
            const float* const rowp = w0 + __float_as_int(dy.x);
            const float fy = dy.y;
            const float wy = dy.z;
            #pragma unroll
            for (int sx = 0; sx < 2; ++sx) {
                const float4 dx = sx ? dx1 : dx0;
                const int cxi  = __float_as_int(dx.x);
                const float fx = dx.y;
                const float wx = dx.z;
                const float v00 = rowp[cxi];
                const float v01 = rowp[cxi + 1];
                const float v10 = rowp[cxi + ldsw];
                const float v11 = rowp[cxi + ldsw + 1];
                const float top = v00 + (v01 - v00) * fx;
                const float bot = v10 + (v11 - v10) * fx;
                acc += wy * wx * (top + (bot - top) * fy);
            }
        }
        out[(size_t)r * ROI_ELEMS + (size_t)c0 * BINS + t] = acc;
    }
}

extern "C" void kernel_launch(void* const* d_in, const int* in_sizes, int n_in,
                              void* d_out, int out_size, void* d_ws, size_t ws_size,
                              hipStream_t stream) {
    const float* x2    = (const float*)d_in[0];
    const float* x3    = (const float*)d_in[1];
    const float* x4    = (const float*)d_in[2];
    const float* x5    = (const float*)d_in[3];
    const float* boxes = (const float*)d_in[4];
    float* out = (float*)d_out;

    dim3 grid(NROI, NGROUP);
    roi_pool_kernel<<<grid, 256, 0, stream>>>(x2, x3, x4, x5, boxes, out);
}

// Round 7
// 222.067 us; speedup vs baseline: 1.2280x; 1.2280x over previous
//
#include <hip/hip_runtime.h>

#define NOUT 7
#define NROI 512
#define NCH 256
#define BINS (NOUT * NOUT)        // 49
#define ROI_ELEMS (NCH * BINS)    // 12544
#define CHUNKS (ROI_ELEMS / 256)  // 49 blocks of 256 threads per roi

// float4 with 4-byte alignment: dword-aligned but not 16B-aligned loads
// (gfx950 handles this; R3 validated dwordx2 at 4B alignment).
typedef float f4u __attribute__((ext_vector_type(4), aligned(4)));

__global__ __launch_bounds__(256) void roi_pool_kernel(
    const float* __restrict__ x2,
    const float* __restrict__ x3,
    const float* __restrict__ x4,
    const float* __restrict__ x5,
    const float* __restrict__ boxes,
    float* __restrict__ out)
{
    const int r     = blockIdx.x;  // roi 0..511
    const int chunk = blockIdx.y;  // 0..48
    const int t     = threadIdx.x; // 0..255

    // y (per ph): sdyA = { asfloat(y0a*W), asfloat(y0b*W), rw0, rw1 },
    //             sdyB = { rw2, rw3 }   rw = 0.25*valid_y*{1-fy, fy} per sample
    // x fast (per pw): sdxW = xw[4] (both samples' lerp+valid weights in a
    //                  4-wide span), sdxC = span base xb
    // x slow (per pw): sdxP = { asfloat(ia), asfloat(ib), wa0, wa1 },
    //                  sdxQ = { wb0, wb1 }   (2-tap weights per x-sample)
    __shared__ float4 sdyA[NOUT];
    __shared__ float2 sdyB[NOUT];
    __shared__ float4 sdxW[NOUT];
    __shared__ int    sdxC[NOUT];
    __shared__ float4 sdxP[NOUT];
    __shared__ float2 sdxQ[NOUT];
    __shared__ int    sfast;
    __shared__ const float* sbase;   // feat + b*C*H*W
    __shared__ int sW, sHW;

    if (t < 32) {
        const float bx1 = boxes[4 * r + 0];
        const float by1 = boxes[4 * r + 1];
        const float bx2 = boxes[4 * r + 2];
        const float by2 = boxes[4 * r + 3];
        const float sz  = sqrtf((bx2 - bx1) * (by2 - by1));
        float lvlf = floorf(4.0f + log2f(sz / 224.0f + 1e-8f));
        lvlf = fminf(fmaxf(lvlf, 2.0f), 5.0f);
        const int level = (int)lvlf - 2;

        int H, W; float scale; const float* feat;
        if (level == 0)      { H = 200; W = 304; scale = 0.25f;    feat = x2; }
        else if (level == 1) { H = 100; W = 152; scale = 0.125f;   feat = x3; }
        else if (level == 2) { H = 50;  W = 76;  scale = 0.0625f;  feat = x4; }
        else                 { H = 25;  W = 38;  scale = 0.03125f; feat = x5; }

        const float X1 = bx1 * scale - 0.5f;
        const float Y1 = by1 * scale - 0.5f;
        const float X2 = bx2 * scale - 0.5f;
        const float Y2 = by2 * scale - 0.5f;
        const float bw = (X2 - X1) * (1.0f / NOUT);
        const float bh = (Y2 - Y1) * (1.0f / NOUT);

        bool okl = true;   // per-lane fast-path fitness (x lanes only)

        if (t < NOUT) {
            // y descriptors for output row ph = t (samples at ph+0.25, ph+0.75)
            const int ph = t;
            float ca = Y1 + ((float)ph + 0.25f) * bh;
            float cb = Y1 + ((float)ph + 0.75f) * bh;
            const float va = ((ca >= -1.0f) && (ca <= (float)H)) ? 0.25f : 0.0f;
            const float vb = ((cb >= -1.0f) && (cb <= (float)H)) ? 0.25f : 0.0f;
            ca = fminf(fmaxf(ca, 0.0f), (float)(H - 1));
            cb = fminf(fmaxf(cb, 0.0f), (float)(H - 1));
            const int ia = min((int)floorf(ca), H - 2);   // i1 = i0+1 normalization
            const int ib = min((int)floorf(cb), H - 2);
            const float fya = ca - (float)ia;
            const float fyb = cb - (float)ib;
            sdyA[ph] = make_float4(__int_as_float(ia * W), __int_as_float(ib * W),
                                   va * (1.0f - fya), va * fya);
            sdyB[ph] = make_float2(vb * (1.0f - fyb), vb * fyb);
        } else if (t >= 8 && t < 8 + NOUT) {
            // x descriptors for output col pw = t-8
            const int pw = t - 8;
            float ca = X1 + ((float)pw + 0.25f) * bw;
            float cb = X1 + ((float)pw + 0.75f) * bw;
            const float va = ((ca >= -1.0f) && (ca <= (float)W)) ? 1.0f : 0.0f;
            const float vb = ((cb >= -1.0f) && (cb <= (float)W)) ? 1.0f : 0.0f;
            ca = fminf(fmaxf(ca, 0.0f), (float)(W - 1));
            cb = fminf(fmaxf(cb, 0.0f), (float)(W - 1));
            const int ia = min((int)floorf(ca), W - 2);
            const int ib = min((int)floorf(cb), W - 2);
            const float fxa = ca - (float)ia;
            const float fxb = cb - (float)ib;

            // slow-path descriptors (always valid)
            sdxP[pw] = make_float4(__int_as_float(ia), __int_as_float(ib),
                                   va * (1.0f - fxa), va * fxa);
            sdxQ[pw] = make_float2(vb * (1.0f - fxb), vb * fxb);

            // fast-path descriptors (valid iff both patches fit [xb, xb+3])
            const int xb = min(ia, W - 4);
            const int d0 = ia - xb;          // 0..2
            const int d1 = ib - xb;          // >= d0; fast iff <= 2
            okl = (d1 <= 2);
            float xw[4];
            #pragma unroll
            for (int k = 0; k < 4; ++k) {
                float w = 0.0f;
                w += va * ((k == d0) ? (1.0f - fxa) : (k == d0 + 1) ? fxa : 0.0f);
                w += vb * ((k == d1) ? (1.0f - fxb) : (k == d1 + 1) ? fxb : 0.0f);
                xw[k] = w;
            }
            sdxW[pw] = make_float4(xw[0], xw[1], xw[2], xw[3]);
            sdxC[pw] = xb;
        }

        // collect per-pw fitness (lanes 8..14); inactive lanes contribute 0
        const unsigned long long bal = __ballot(okl);
        if (t == 31) {
            const int b = r >> 8;
            sbase = feat + (size_t)b * NCH * H * W;
            sW    = W;
            sHW   = H * W;
            sfast = (((bal >> 8) & 0x7Full) == 0x7Full);
        }
    }
    __syncthreads();

    const float* const base = sbase;
    const int W  = sW;
    const int HW = sHW;
    const int fast = sfast;

    // one output element per thread
    const int i   = chunk * 256 + t;      // 0..12543 within this roi
    const int c   = i / BINS;             // channel 0..255
    const int bin = i - c * BINS;         // 0..48
    const int ph  = bin / NOUT;
    const int pw  = bin - ph * NOUT;

    const float4 yA = sdyA[ph];
    const float2 yB = sdyB[ph];

    const float* const f  = base + (size_t)c * HW;
    const float* const pa = f + __float_as_int(yA.x);   // row y0a
    const float* const pb = f + __float_as_int(yA.y);   // row y0b

    float d0, d1, d2, d3;
    if (fast) {
        const float4 xw = sdxW[pw];
        const int    xb = sdxC[pw];
        const f4u r0 = *(const f4u*)(pa + xb);
        const f4u r1 = *(const f4u*)(pa + W + xb);
        const f4u r2 = *(const f4u*)(pb + xb);
        const f4u r3 = *(const f4u*)(pb + W + xb);
        d0 = r0.x * xw.x + r0.y * xw.y + r0.z * xw.z + r0.w * xw.w;
        d1 = r1.x * xw.x + r1.y * xw.y + r1.z * xw.z + r1.w * xw.w;
        d2 = r2.x * xw.x + r2.y * xw.y + r2.z * xw.z + r2.w * xw.w;
        d3 = r3.x * xw.x + r3.y * xw.y + r3.z * xw.z + r3.w * xw.w;
    } else {
        const float4 xp = sdxP[pw];
        const float2 xq = sdxQ[pw];
        const int ia = __float_as_int(xp.x);
        const int ib = __float_as_int(xp.y);
        const float2 a0 = *(const float2*)(pa + ia);
        const float2 b0 = *(const float2*)(pa + ib);
        const float2 a1 = *(const float2*)(pa + W + ia);
        const float2 b1 = *(const float2*)(pa + W + ib);
        const float2 a2 = *(const float2*)(pb + ia);
        const float2 b2 = *(const float2*)(pb + ib);
        const float2 a3 = *(const float2*)(pb + W + ia);
        const float2 b3 = *(const float2*)(pb + W + ib);
        d0 = a0.x * xp.z + a0.y * xp.w + b0.x * xq.x + b0.y * xq.y;
        d1 = a1.x * xp.z + a1.y * xp.w + b1.x * xq.x + b1.y * xq.y;
        d2 = a2.x * xp.z + a2.y * xp.w + b2.x * xq.x + b2.y * xq.y;
        d3 = a3.x * xp.z + a3.y * xp.w + b3.x * xq.x + b3.y * xq.y;
    }

    const float acc = yA.z * d0 + yA.w * d1 + yB.x * d2 + yB.y * d3;
    out[(size_t)r * ROI_ELEMS + i] = acc;
}

extern "C" void kernel_launch(void* const* d_in, const int* in_sizes, int n_in,
                              void* d_out, int out_size, void* d_ws, size_t ws_size,
                              hipStream_t stream) {
    const float* x2    = (const float*)d_in[0];
    const float* x3    = (const float*)d_in[1];
    const float* x4    = (const float*)d_in[2];
    const float* x5    = (const float*)d_in[3];
    const float* boxes = (const float*)d_in[4];
    float* out = (float*)d_out;

    dim3 grid(NROI, CHUNKS);
    roi_pool_kernel<<<grid, 256, 0, stream>>>(x2, x3, x4, x5, boxes, out);
}